// Round 7
// baseline (559.839 us; speedup 1.0000x reference)
//
#include <hip/hip_runtime.h>
#include <math.h>

#define HIDDEN 1024
#define NSEQ   512
#define BATCH  32
#define EDIM   2048
#define SDIM   128
#define UVN    (2 * EDIM + SDIM)   // 4224

using short8  = __attribute__((ext_vector_type(8))) short;
using float4x = __attribute__((ext_vector_type(4))) float;

__device__ __forceinline__ ushort f2bf(float f) {
    unsigned u = __float_as_uint(f);
    u += 0x7FFFu + ((u >> 16) & 1u);   // RNE
    return (ushort)(u >> 16);
}
__device__ __forceinline__ float bf2f(ushort h) {
    return __uint_as_float(((unsigned)h) << 16);
}

// global->LDS direct copy, 16B per lane. LDS dest = wave-uniform base + lane*16.
#define ASYNC16(gp, lp) __builtin_amdgcn_global_load_lds( \
    (const __attribute__((address_space(1))) unsigned int*)(unsigned long long)(const void*)(gp), \
    (__attribute__((address_space(3))) unsigned int*)(unsigned int)(unsigned long long)(const void*)(lp), \
    16, 0, 0)

// ---------------------------------------------------------------------------
// Prep (one launch): rope sin/cos table + both weight transposes.
// blocks [0,4224): uv_w (1024x4224) -> uv_wt; [4224,6272): o_w (2048x1024)
// -> o_wt; [6272,6400): sin/cos table (f64).
// ---------------------------------------------------------------------------
__device__ __forceinline__ void transpose_tile(const float* __restrict__ src,
                                               ushort* __restrict__ dst,
                                               int R, int Cc, int bx, int by,
                                               float (*tile)[33]) {
    const int lx = threadIdx.x & 31;
    const int gy = threadIdx.x >> 5;
#pragma unroll
    for (int i = 0; i < 4; ++i) {
        int r = by * 32 + gy + i * 8;
        tile[gy + i * 8][lx] = src[(size_t)r * Cc + bx * 32 + lx];
    }
    __syncthreads();
#pragma unroll
    for (int i = 0; i < 4; ++i) {
        int c = bx * 32 + gy + i * 8;
        dst[(size_t)c * R + by * 32 + lx] = f2bf(tile[lx][gy + i * 8]);
    }
}

__global__ __launch_bounds__(256) void prep_kernel(const float* __restrict__ uv_w,
                                                   ushort* __restrict__ uv_wt,
                                                   const float* __restrict__ o_w,
                                                   ushort* __restrict__ o_wt,
                                                   float* __restrict__ sin_t,
                                                   float* __restrict__ cos_t) {
    __shared__ float tile[32][33];
    const int blk = blockIdx.x;
    if (blk < 4224) {
        transpose_tile(uv_w, uv_wt, HIDDEN, UVN, blk % 132, blk / 132, tile);
    } else if (blk < 6272) {
        const int r = blk - 4224;
        transpose_tile(o_w, o_wt, EDIM, HIDDEN, r % 32, r / 32, tile);
    } else {
        const int r = blk - 6272;
        const int i = r * 4 + (threadIdx.x >> 6);
        const int j = threadIdx.x & 63;
        double inv = pow(10000.0, (double)j / 64.0);
        double ang = (double)i * inv;
        sin_t[i * 64 + j] = (float)sin(ang);
        cos_t[i * 64 + j] = (float)cos(ang);
    }
}

// ---------------------------------------------------------------------------
// LayerNorm: one block per token, 256 threads, float4/thread. bf16 output.
// ---------------------------------------------------------------------------
__global__ __launch_bounds__(256) void ln_kernel(const float* __restrict__ x,
                                                 const float* __restrict__ g,
                                                 const float* __restrict__ b,
                                                 ushort* __restrict__ xn) {
    const size_t t = blockIdx.x;
    const int tid = threadIdx.x;
    const float4 v = ((const float4*)(x + t * HIDDEN))[tid];
    float s = v.x + v.y + v.z + v.w;
#pragma unroll
    for (int off = 32; off > 0; off >>= 1) s += __shfl_down(s, off);
    __shared__ float red[4];
    const int wid = tid >> 6, lane = tid & 63;
    if (lane == 0) red[wid] = s;
    __syncthreads();
    const float mean = (red[0] + red[1] + red[2] + red[3]) * (1.0f / HIDDEN);
    __syncthreads();
    const float dx = v.x - mean, dy = v.y - mean, dz = v.z - mean, dw = v.w - mean;
    float s2 = dx * dx + dy * dy + dz * dz + dw * dw;
#pragma unroll
    for (int off = 32; off > 0; off >>= 1) s2 += __shfl_down(s2, off);
    if (lane == 0) red[wid] = s2;
    __syncthreads();
    const float var = (red[0] + red[1] + red[2] + red[3]) * (1.0f / HIDDEN);
    const float rs = rsqrtf(var + 1e-5f);
    const float4 gv = ((const float4*)g)[tid];
    const float4 bv = ((const float4*)b)[tid];
    ushort4 o;
    o.x = f2bf(dx * rs * gv.x + bv.x);
    o.y = f2bf(dy * rs * gv.y + bv.y);
    o.z = f2bf(dz * rs * gv.z + bv.z);
    o.w = f2bf(dw * rs * gv.w + bv.w);
    ((ushort4*)(xn + t * HIDDEN))[tid] = o;
}

// ---------------------------------------------------------------------------
// 256x256 deep-pipelined 8-wave MFMA core (R1 version — best for pv, K=512).
// ---------------------------------------------------------------------------
__device__ __forceinline__ void mfma_core_256(const ushort* __restrict__ A,
                                              const ushort* __restrict__ Bt,
                                              const int lda, const int ldb, const int K,
                                              const int m0, const int n0,
                                              char* smem,
                                              float4x (&acc)[8][4]) {
    const int tid = threadIdx.x;
    const int l = tid & 63, w = tid >> 6;
    const int wm = w >> 2, wn = w & 3;

    const int srow = l >> 2;
    const int kcol = (w & 1) * 32 + (((tid & 3) ^ ((l >> 3) & 3)) << 3);
    const int rb0  = w >> 1;
    const ushort* gA[4];
    const ushort* gB[4];
#pragma unroll
    for (int j = 0; j < 4; ++j) {
        const int row = (j * 4 + rb0) * 16 + srow;
        gA[j] = A  + (size_t)(m0 + row) * lda + kcol;
        gB[j] = Bt + (size_t)(n0 + row) * ldb + kcol;
    }
    char* const ldsA = smem;
    char* const ldsB = smem + 65536;
    const int wdst = w * 1024;

#define STG_A(buf, j, t)  ASYNC16(gA[j] + (size_t)(t) * 64, ldsA + (buf) * 32768 + (j) * 8192 + wdst)
#define STG_B(buf, j, t)  ASYNC16(gB[j] + (size_t)(t) * 64, ldsB + (buf) * 32768 + (j) * 8192 + wdst)
#define RAWBAR() do { __builtin_amdgcn_sched_barrier(0); __builtin_amdgcn_s_barrier(); \
                      __builtin_amdgcn_sched_barrier(0); } while (0)
#define WAITV(N) asm volatile("s_waitcnt vmcnt(" #N ")" ::: "memory")

    const int LB = (l & 15) * 64 + (((l >> 4) ^ ((l >> 1) & 3)) << 4);
    const int rbbA0 = wm * 4;
    const int rbbA1 = 8 + wm * 4;
    const int cbbB0 = wn * 2;
    const int cbbB1 = 8 + wn * 2;

    const int KT = K >> 6;

    STG_A(0, 0, 0); STG_A(0, 1, 0);
    STG_B(0, 0, 0); STG_B(0, 1, 0);
    STG_B(0, 2, 0); STG_B(0, 3, 0);
    STG_A(0, 2, 0); STG_A(0, 3, 0);
    STG_A(1, 0, 1); STG_A(1, 1, 1);
    STG_B(1, 0, 1); STG_B(1, 1, 1);
    STG_B(1, 2, 1); STG_B(1, 3, 1);
    WAITV(10);
    RAWBAR();

    for (int t = 0; t < KT; ++t) {
        const int buf = t & 1;
        const char* Ab = ldsA + buf * 32768;
        const char* Bb = ldsB + buf * 32768;
        short8 a[4][2], b0[2][2], b1[2][2];

#pragma unroll
        for (int mi = 0; mi < 4; ++mi) {
            a[mi][0] = *(const short8*)(Ab + (rbbA0 + mi) * 2048 + LB);
            a[mi][1] = *(const short8*)(Ab + (rbbA0 + mi) * 2048 + 1024 + LB);
        }
#pragma unroll
        for (int ni = 0; ni < 2; ++ni) {
            b0[ni][0] = *(const short8*)(Bb + (cbbB0 + ni) * 2048 + LB);
            b0[ni][1] = *(const short8*)(Bb + (cbbB0 + ni) * 2048 + 1024 + LB);
        }
        if (t + 1 < KT) { STG_A(buf ^ 1, 2, t + 1); STG_A(buf ^ 1, 3, t + 1); }
        RAWBAR();
        __builtin_amdgcn_s_setprio(1);
#pragma unroll
        for (int mi = 0; mi < 4; ++mi)
#pragma unroll
            for (int ni = 0; ni < 2; ++ni) {
                acc[mi][ni] = __builtin_amdgcn_mfma_f32_16x16x32_bf16(a[mi][0], b0[ni][0], acc[mi][ni], 0, 0, 0);
                acc[mi][ni] = __builtin_amdgcn_mfma_f32_16x16x32_bf16(a[mi][1], b0[ni][1], acc[mi][ni], 0, 0, 0);
            }
        __builtin_amdgcn_s_setprio(0);
        if (t < KT - 1) { WAITV(10); } else { WAITV(2); }
        RAWBAR();

#pragma unroll
        for (int ni = 0; ni < 2; ++ni) {
            b1[ni][0] = *(const short8*)(Bb + (cbbB1 + ni) * 2048 + LB);
            b1[ni][1] = *(const short8*)(Bb + (cbbB1 + ni) * 2048 + 1024 + LB);
        }
        if (t + 2 < KT) { STG_A(buf, 0, t + 2); STG_A(buf, 1, t + 2); }
        RAWBAR();
        __builtin_amdgcn_s_setprio(1);
#pragma unroll
        for (int mi = 0; mi < 4; ++mi)
#pragma unroll
            for (int ni = 0; ni < 2; ++ni) {
                acc[mi][2 + ni] = __builtin_amdgcn_mfma_f32_16x16x32_bf16(a[mi][0], b1[ni][0], acc[mi][2 + ni], 0, 0, 0);
                acc[mi][2 + ni] = __builtin_amdgcn_mfma_f32_16x16x32_bf16(a[mi][1], b1[ni][1], acc[mi][2 + ni], 0, 0, 0);
            }
        __builtin_amdgcn_s_setprio(0);
        if (t < KT - 2) { WAITV(10); } else if (t == KT - 2) { WAITV(8); } else { WAITV(0); }
        RAWBAR();

#pragma unroll
        for (int mi = 0; mi < 4; ++mi) {
            a[mi][0] = *(const short8*)(Ab + (rbbA1 + mi) * 2048 + LB);
            a[mi][1] = *(const short8*)(Ab + (rbbA1 + mi) * 2048 + 1024 + LB);
        }
        if (t + 2 < KT) {
            STG_B(buf, 0, t + 2); STG_B(buf, 1, t + 2);
            STG_B(buf, 2, t + 2); STG_B(buf, 3, t + 2);
        }
        RAWBAR();
        __builtin_amdgcn_s_setprio(1);
#pragma unroll
        for (int mi = 0; mi < 4; ++mi)
#pragma unroll
            for (int ni = 0; ni < 2; ++ni) {
                acc[4 + mi][2 + ni] = __builtin_amdgcn_mfma_f32_16x16x32_bf16(a[mi][0], b1[ni][0], acc[4 + mi][2 + ni], 0, 0, 0);
                acc[4 + mi][2 + ni] = __builtin_amdgcn_mfma_f32_16x16x32_bf16(a[mi][1], b1[ni][1], acc[4 + mi][2 + ni], 0, 0, 0);
            }
#pragma unroll
        for (int mi = 0; mi < 4; ++mi)
#pragma unroll
            for (int ni = 0; ni < 2; ++ni) {
                acc[4 + mi][ni] = __builtin_amdgcn_mfma_f32_16x16x32_bf16(a[mi][0], b0[ni][0], acc[4 + mi][ni], 0, 0, 0);
                acc[4 + mi][ni] = __builtin_amdgcn_mfma_f32_16x16x32_bf16(a[mi][1], b0[ni][1], acc[4 + mi][ni], 0, 0, 0);
            }
        __builtin_amdgcn_s_setprio(0);
        if (t < KT - 2) { WAITV(10); } else if (t == KT - 2) { WAITV(4); }
        RAWBAR();
    }
#undef STG_A
#undef STG_B
#undef RAWBAR
#undef WAITV
}

template <typename F>
__device__ __forceinline__ void epilogue_256(const float4x (&acc)[8][4],
                                             int m0, int n0, F body) {
    const int tid = threadIdx.x;
    const int l = tid & 63, w = tid >> 6;
    const int wm = w >> 2, wn = w & 3;
    const int lrow = (l >> 4) << 2, lcol = l & 15;
#pragma unroll
    for (int i = 0; i < 8; ++i)
#pragma unroll
        for (int j = 0; j < 4; ++j)
#pragma unroll
            for (int r = 0; r < 4; ++r) {
                const int m = m0 + (i >> 2) * 128 + wm * 64 + (i & 3) * 16 + lrow + r;
                const int n = n0 + (j >> 1) * 128 + wn * 32 + (j & 1) * 16 + lcol;
                body(m, n, acc[i][j][r]);
            }
}

// ---------------------------------------------------------------------------
// 256x256 16-wave v3 core (measured 859 TF @ K=1024; overhead ~6% @ K=2048).
// ---------------------------------------------------------------------------
__device__ __forceinline__ void mfma_core_v3(const ushort* __restrict__ A,
                                             const ushort* __restrict__ Bt,
                                             const int lda, const int ldb, const int K,
                                             const int m0, const int n0,
                                             char* smem,
                                             float4x (&acc)[4][4]) {
    const int tid = threadIdx.x;
    const int l = tid & 63, w = tid >> 6;        // 16 waves
    const int wm = w >> 2, wn = w & 3;

    const int srow = l >> 2;
    const int kswz = ((l & 3) ^ ((l >> 3) & 3)) << 3;
    const ushort* gA = A + (size_t)(m0 + w * 16 + srow) * lda + kswz;
    const ushort* gB = Bt + (size_t)(n0 + w * 16 + srow) * ldb + kswz;
    char* const ldsA = smem;
    char* const ldsB = smem + 65536;
    const int woff = w * 2048;

    const int LB = (l & 15) * 64 + (((l >> 4) ^ ((l >> 1) & 3)) << 4);
    const int rbb = wm * 4, cbb = wn * 4;
    const int KT = K >> 6;

    ASYNC16(gA, ldsA + woff);
    ASYNC16(gA + 32, ldsA + woff + 1024);
    ASYNC16(gB, ldsB + woff);
    ASYNC16(gB + 32, ldsB + woff + 1024);
    __syncthreads();

    for (int t = 0; t < KT; ++t) {
        const int buf = t & 1;
        const char* Ab = ldsA + buf * 32768;
        const char* Bb = ldsB + buf * 32768;
        if (t + 1 < KT) {
            const size_t g = (size_t)(t + 1) * 64;
            char* dA = ldsA + (buf ^ 1) * 32768 + woff;
            char* dB = ldsB + (buf ^ 1) * 32768 + woff;
            ASYNC16(gA + g, dA);
            ASYNC16(gA + g + 32, dA + 1024);
            ASYNC16(gB + g, dB);
            ASYNC16(gB + g + 32, dB + 1024);
        }
        __builtin_amdgcn_sched_barrier(0);
#pragma unroll
        for (int kh = 0; kh < 2; ++kh) {
            short8 a[4], b[4];
#pragma unroll
            for (int i = 0; i < 4; ++i) {
                a[i] = *(const short8*)(Ab + (rbb + i) * 2048 + kh * 1024 + LB);
                b[i] = *(const short8*)(Bb + (cbb + i) * 2048 + kh * 1024 + LB);
            }
            __builtin_amdgcn_s_setprio(1);
#pragma unroll
            for (int i = 0; i < 4; ++i)
#pragma unroll
                for (int j = 0; j < 4; ++j)
                    acc[i][j] = __builtin_amdgcn_mfma_f32_16x16x32_bf16(
                        a[i], b[j], acc[i][j], 0, 0, 0);
            __builtin_amdgcn_s_setprio(0);
        }
        __syncthreads();
    }
}

template <typename F>
__device__ __forceinline__ void epilogue_v3(const float4x (&acc)[4][4],
                                            int m0, int n0, F body) {
    const int tid = threadIdx.x;
    const int l = tid & 63, w = tid >> 6;
    const int wm = w >> 2, wn = w & 3;
    const int lrow = (l >> 4) << 2, lcol = l & 15;
#pragma unroll
    for (int i = 0; i < 4; ++i)
#pragma unroll
        for (int j = 0; j < 4; ++j)
#pragma unroll
            for (int r = 0; r < 4; ++r) {
                const int m = m0 + wm * 64 + i * 16 + lrow + r;
                const int n = n0 + wn * 64 + j * 16 + lcol;
                body(m, n, acc[i][j][r]);
            }
}

// ---------------------------------------------------------------------------
// GEMM1: v3 core. n-tiles 0..7 -> U, 8..15 -> VT, 16 -> BASE (128 valid cols;
// the invalid half reads workspace garbage and is discarded via n<UVN guard).
// ---------------------------------------------------------------------------
__global__ __launch_bounds__(1024, 4) void gemm_uv3(const ushort* __restrict__ A,
                                                    const ushort* __restrict__ Bt,
                                                    const float* __restrict__ bias,
                                                    ushort* __restrict__ U,
                                                    ushort* __restrict__ VT,
                                                    float* __restrict__ BASE) {
    __shared__ __align__(16) char smem[131072];
    float4x acc[4][4] = {};
    const int n0 = blockIdx.x * 256, m0 = blockIdx.y * 256;
    mfma_core_v3(A, Bt, HIDDEN, HIDDEN, HIDDEN, m0, n0, smem, acc);
    if (blockIdx.x < 8) {
        epilogue_v3(acc, m0, n0, [&](int m, int n, float aval) {
            float val = aval + bias[n];
            val = val / (1.0f + expf(-val));
            U[(size_t)m * EDIM + n] = f2bf(val);
        });
    } else if (blockIdx.x < 16) {
        epilogue_v3(acc, m0, n0, [&](int m, int n, float aval) {
            float val = aval + bias[n];
            val = val / (1.0f + expf(-val));
            const int e = n - EDIM;
            const int b = m >> 9;
            const int s = m & (NSEQ - 1);
            VT[((size_t)b * EDIM + e) * NSEQ + s] = f2bf(val);
        });
    } else {
        epilogue_v3(acc, m0, n0, [&](int m, int n, float aval) {
            if (n < UVN) {
                float val = aval + bias[n];
                val = val / (1.0f + expf(-val));
                BASE[(size_t)m * SDIM + (n - 2 * EDIM)] = val;
            }
        });
    }
}

// ---------------------------------------------------------------------------
// Rope: base(r,128) -> q,k split into bf16 head + bf16 residual.
// ---------------------------------------------------------------------------
__global__ __launch_bounds__(128) void rope_kernel(const float* __restrict__ base,
                                                   const float* __restrict__ gamma,
                                                   const float* __restrict__ beta,
                                                   const float* __restrict__ sin_t,
                                                   const float* __restrict__ cos_t,
                                                   ushort* __restrict__ qh,
                                                   ushort* __restrict__ ql,
                                                   ushort* __restrict__ kh,
                                                   ushort* __restrict__ kl) {
    const size_t t = blockIdx.x;
    const int d = threadIdx.x;
    const int pos = (int)(t & (NSEQ - 1));
    __shared__ float vq[128], vk[128];
    const float bval = base[t * SDIM + d];
    vq[d] = bval * gamma[d] + beta[d];
    vk[d] = bval * gamma[SDIM + d] + beta[SDIM + d];
    __syncthreads();
    const int h = d & 63;
    const float sn = sin_t[pos * 64 + h];
    const float cs = cos_t[pos * 64 + h];
    float oq, ok;
    if (d < 64) {
        oq = vq[d] * cs - vq[d + 64] * sn;
        ok = vk[d] * cs - vk[d + 64] * sn;
    } else {
        oq = vq[d] * cs + vq[d - 64] * sn;
        ok = vk[d] * cs + vk[d - 64] * sn;
    }
    const ushort qhv = f2bf(oq);
    const ushort khv = f2bf(ok);
    qh[t * SDIM + d] = qhv;
    ql[t * SDIM + d] = f2bf(oq - bf2f(qhv));
    kh[t * SDIM + d] = khv;
    kl[t * SDIM + d] = f2bf(ok - bf2f(khv));
}

// ---------------------------------------------------------------------------
// QK^T per batch via bf16x3 MFMA: qk = qh*kh + qh*kl + ql*kh.
// ---------------------------------------------------------------------------
__global__ __launch_bounds__(256, 4) void gemm_qk3(const ushort* __restrict__ qh,
                                                   const ushort* __restrict__ ql,
                                                   const ushort* __restrict__ kh,
                                                   const ushort* __restrict__ kl,
                                                   const float* __restrict__ mask,
                                                   const float* __restrict__ w,
                                                   ushort* __restrict__ km) {
    __shared__ __align__(16) char smem[32768];
    float4x acc[4][4] = {};
    const int b = blockIdx.z;
    const int tid = threadIdx.x;
    const int l = tid & 63, wv = tid >> 6;
    const int wm = wv & 1, wn = wv >> 1;
    const int m0 = blockIdx.y * 128, n0 = blockIdx.x * 128;
    const size_t boff = (size_t)b * NSEQ * SDIM;

    const int srow = l >> 2;
    const int kswz = ((l & 3) ^ ((l >> 3) & 3)) << 3;
    const size_t r0 = (size_t)(m0 + wv * 16 + srow) * SDIM + kswz;
    const size_t r1 = r0 + (size_t)64 * SDIM;
    const size_t c0 = (size_t)(n0 + wv * 16 + srow) * SDIM + kswz;
    const size_t c1 = c0 + (size_t)64 * SDIM;
    const ushort* gqh = qh + boff;
    const ushort* gql = ql + boff;
    const ushort* gkh = kh + boff;
    const ushort* gkl = kl + boff;

    const int LB = (l & 15) * 64 + (((l >> 4) ^ ((l >> 1) & 3)) << 4);

    for (int t = 0; t < 4; ++t) {
        const int g = t * 32;
        ASYNC16(gqh + r0 + g, smem + wv * 1024);
        ASYNC16(gqh + r1 + g, smem + (4 + wv) * 1024);
        ASYNC16(gql + r0 + g, smem + 8192 + wv * 1024);
        ASYNC16(gql + r1 + g, smem + 8192 + (4 + wv) * 1024);
        ASYNC16(gkh + c0 + g, smem + 16384 + wv * 1024);
        ASYNC16(gkh + c1 + g, smem + 16384 + (4 + wv) * 1024);
        ASYNC16(gkl + c0 + g, smem + 24576 + wv * 1024);
        ASYNC16(gkl + c1 + g, smem + 24576 + (4 + wv) * 1024);
        __syncthreads();
        short8 ah[4], bh[4], bl[4];
#pragma unroll
        for (int i = 0; i < 4; ++i) {
            ah[i] = *(const short8*)(smem + (wm * 4 + i) * 1024 + LB);
            bh[i] = *(const short8*)(smem + 16384 + (wn * 4 + i) * 1024 + LB);
            bl[i] = *(const short8*)(smem + 24576 + (wn * 4 + i) * 1024 + LB);
        }
        __builtin_amdgcn_s_setprio(1);
#pragma unroll
        for (int i = 0; i < 4; ++i)
#pragma unroll
            for (int j = 0; j < 4; ++j) {
                acc[i][j] = __builtin_amdgcn_mfma_f32_16x16x32_bf16(ah[i], bh[j], acc[i][j], 0, 0, 0);
                acc[i][j] = __builtin_amdgcn_mfma_f32_16x16x32_bf16(ah[i], bl[j], acc[i][j], 0, 0, 0);
            }
        __builtin_amdgcn_s_setprio(0);
        short8 al[4];
#pragma unroll
        for (int i = 0; i < 4; ++i)
            al[i] = *(const short8*)(smem + 8192 + (wm * 4 + i) * 1024 + LB);
        __builtin_amdgcn_s_setprio(1);
#pragma unroll
        for (int i = 0; i < 4; ++i)
#pragma unroll
            for (int j = 0; j < 4; ++j)
                acc[i][j] = __builtin_amdgcn_mfma_f32_16x16x32_bf16(al[i], bh[j], acc[i][j], 0, 0, 0);
        __builtin_amdgcn_s_setprio(0);
        if (t < 3) __syncthreads();
    }

    const int lrow = (l >> 4) << 2, lcol = l & 15;
    const float inv512 = 1.0f / 512.0f;
#pragma unroll
    for (int i = 0; i < 4; ++i)
#pragma unroll
        for (int j = 0; j < 4; ++j)
#pragma unroll
            for (int r = 0; r < 4; ++r) {
                const int m = m0 + wm * 64 + i * 16 + lrow + r;
                const int n = n0 + wn * 64 + j * 16 + lcol;
                const float mterm = (1.0f - mask[b * NSEQ + n]) * -1e12f;
                float val = (acc[i][j][r] + mterm) * inv512 + w[511 + n - m];
                val = fmaxf(val, 0.0f);
                km[(size_t)b * NSEQ * NSEQ + (size_t)m * NSEQ + n] = f2bf(val * val);
            }
}

// ---------------------------------------------------------------------------
// kernel @ V per batch (8-wave 256 core, K=512), gated by u in-place.
// ---------------------------------------------------------------------------
__global__ __launch_bounds__(512) void gemm_pv2(const ushort* __restrict__ km,
                                                const ushort* __restrict__ vT,
                                                ushort* __restrict__ ug) {
    __shared__ __align__(16) char smem[131072];
    float4x acc[8][4] = {};
    const int b = blockIdx.z;
    const int n0 = blockIdx.x * 256, m0 = blockIdx.y * 256;
    mfma_core_256(km + (size_t)b * NSEQ * NSEQ, vT + (size_t)b * EDIM * NSEQ,
                  NSEQ, NSEQ, NSEQ, m0, n0, smem, acc);
    const size_t tokbase = (size_t)b * NSEQ;
    epilogue_256(acc, m0, n0, [&](int m, int n, float aval) {
        const size_t idx = (tokbase + m) * EDIM + n;
        ug[idx] = f2bf(bf2f(ug[idx]) * aval);
    });
}

// ---------------------------------------------------------------------------
// GEMM2: out = gated @ o_w + o_b + x (v3 16-wave core, K=2048, fp32 out).
// ---------------------------------------------------------------------------
__global__ __launch_bounds__(1024, 4) void gemm_out5(const ushort* __restrict__ A,
                                                     const ushort* __restrict__ Bt,
                                                     const float* __restrict__ ob,
                                                     const float* __restrict__ x,
                                                     float* __restrict__ out) {
    __shared__ __align__(16) char smem[131072];
    float4x acc[4][4] = {};
    const int n0 = blockIdx.x * 256, m0 = blockIdx.y * 256;
    mfma_core_v3(A, Bt, EDIM, EDIM, EDIM, m0, n0, smem, acc);
    epilogue_v3(acc, m0, n0, [&](int m, int n, float aval) {
        out[(size_t)m * HIDDEN + n] = aval + ob[n] + x[(size_t)m * HIDDEN + n];
    });
}

// ---------------------------------------------------------------------------
// Workspace: need = C*5505024 + 13107200 bytes (unchanged).
// xn overlay after gemm_uv: qh/ql/kh/kl bf16 (C*131072 each) + km bf16.
// ---------------------------------------------------------------------------
extern "C" void kernel_launch(void* const* d_in, const int* in_sizes, int n_in,
                              void* d_out, int out_size, void* d_ws, size_t ws_size,
                              hipStream_t stream) {
    const float* x     = (const float*)d_in[0];
    const float* mask  = (const float*)d_in[1];
    const float* gamma = (const float*)d_in[2];
    const float* beta  = (const float*)d_in[3];
    const float* w     = (const float*)d_in[4];
    const float* uv_w  = (const float*)d_in[7];
    const float* uv_b  = (const float*)d_in[8];
    const float* o_w   = (const float*)d_in[9];
    const float* o_b   = (const float*)d_in[10];
    const float* ln_g  = (const float*)d_in[11];
    const float* ln_b  = (const float*)d_in[12];
    float* out = (float*)d_out;

    int C = 32;
    while (C > 1) {
        unsigned long long need = (unsigned long long)C * 5505024ull + 13107200ull;
        if (need <= (unsigned long long)ws_size) break;
        C >>= 1;
    }
    const int R = C * NSEQ;

    char* p = (char*)d_ws;
    ushort* xn  = (ushort*)p;  p += (size_t)C * 1048576;
    ushort* u   = (ushort*)p;  p += (size_t)C * 2097152;
    ushort* vT  = (ushort*)p;  p += (size_t)C * 2097152;
    float* base = (float*)p;   p += (size_t)C * 262144;
    float* sint = (float*)p;   p += 131072;
    float* cost = (float*)p;   p += 131072;
    ushort* uv_wt = (ushort*)p; p += 8650752;
    ushort* o_wt  = (ushort*)p; p += 4194304;
    ushort* qh = (ushort*)xn;
    ushort* ql = (ushort*)((char*)xn + (size_t)C * 131072);
    ushort* kh = (ushort*)((char*)xn + (size_t)C * 262144);
    ushort* kl = (ushort*)((char*)xn + (size_t)C * 393216);
    ushort* km = (ushort*)((char*)xn + (size_t)C * 524288);

    hipLaunchKernelGGL(prep_kernel, dim3(6400), dim3(256), 0, stream,
                       uv_w, uv_wt, o_w, o_wt, sint, cost);

    for (int b0 = 0; b0 < BATCH; b0 += C) {
        const float* xc = x + (size_t)b0 * NSEQ * HIDDEN;
        float*       oc = out + (size_t)b0 * NSEQ * HIDDEN;
        const float* mc = mask + (size_t)b0 * NSEQ;
        hipLaunchKernelGGL(ln_kernel, dim3(R), dim3(256), 0, stream, xc, ln_g, ln_b, xn);
        hipLaunchKernelGGL(gemm_uv3, dim3(17, R / 256), dim3(1024), 0, stream,
                           xn, uv_wt, uv_b, u, vT, base);
        hipLaunchKernelGGL(rope_kernel, dim3(R), dim3(128), 0, stream,
                           base, gamma, beta, sint, cost, qh, ql, kh, kl);
        hipLaunchKernelGGL(gemm_qk3, dim3(4, 4, C), dim3(256), 0, stream,
                           qh, ql, kh, kl, mc, w, km);
        hipLaunchKernelGGL(gemm_pv2, dim3(8, 2, C), dim3(512), 0, stream, km, vT, u);
        hipLaunchKernelGGL(gemm_out5, dim3(4, R / 256), dim3(1024), 0, stream,
                           u, o_wt, o_b, xc, oc);
    }
}

// Round 8
// 486.871 us; speedup vs baseline: 1.1499x; 1.1499x over previous
//
#include <hip/hip_runtime.h>
#include <math.h>

#define HIDDEN 1024
#define NSEQ   512
#define BATCH  32
#define EDIM   2048
#define SDIM   128
#define UVN    (2 * EDIM + SDIM)   // 4224

using short8  = __attribute__((ext_vector_type(8))) short;
using float4x = __attribute__((ext_vector_type(4))) float;

__device__ __forceinline__ ushort f2bf(float f) {
    unsigned u = __float_as_uint(f);
    u += 0x7FFFu + ((u >> 16) & 1u);   // RNE
    return (ushort)(u >> 16);
}
__device__ __forceinline__ float bf2f(ushort h) {
    return __uint_as_float(((unsigned)h) << 16);
}

// global->LDS direct copy, 16B per lane. LDS dest = wave-uniform base + lane*16.
#define ASYNC16(gp, lp) __builtin_amdgcn_global_load_lds( \
    (const __attribute__((address_space(1))) unsigned int*)(unsigned long long)(const void*)(gp), \
    (__attribute__((address_space(3))) unsigned int*)(unsigned int)(unsigned long long)(const void*)(lp), \
    16, 0, 0)

// ---------------------------------------------------------------------------
// Prep (one launch): rope sin/cos table + both weight transposes.
// blocks [0,4224): uv_w -> uv_wt; [4224,6272): o_w -> o_wt; [6272,6400): table.
// ---------------------------------------------------------------------------
__device__ __forceinline__ void transpose_tile(const float* __restrict__ src,
                                               ushort* __restrict__ dst,
                                               int R, int Cc, int bx, int by,
                                               float (*tile)[33]) {
    const int lx = threadIdx.x & 31;
    const int gy = threadIdx.x >> 5;
#pragma unroll
    for (int i = 0; i < 4; ++i) {
        int r = by * 32 + gy + i * 8;
        tile[gy + i * 8][lx] = src[(size_t)r * Cc + bx * 32 + lx];
    }
    __syncthreads();
#pragma unroll
    for (int i = 0; i < 4; ++i) {
        int c = bx * 32 + gy + i * 8;
        dst[(size_t)c * R + by * 32 + lx] = f2bf(tile[lx][gy + i * 8]);
    }
}

__global__ __launch_bounds__(256) void prep_kernel(const float* __restrict__ uv_w,
                                                   ushort* __restrict__ uv_wt,
                                                   const float* __restrict__ o_w,
                                                   ushort* __restrict__ o_wt,
                                                   float* __restrict__ sin_t,
                                                   float* __restrict__ cos_t) {
    __shared__ float tile[32][33];
    const int blk = blockIdx.x;
    if (blk < 4224) {
        transpose_tile(uv_w, uv_wt, HIDDEN, UVN, blk % 132, blk / 132, tile);
    } else if (blk < 6272) {
        const int r = blk - 4224;
        transpose_tile(o_w, o_wt, EDIM, HIDDEN, r % 32, r / 32, tile);
    } else {
        const int r = blk - 6272;
        const int i = r * 4 + (threadIdx.x >> 6);
        const int j = threadIdx.x & 63;
        double inv = pow(10000.0, (double)j / 64.0);
        double ang = (double)i * inv;
        sin_t[i * 64 + j] = (float)sin(ang);
        cos_t[i * 64 + j] = (float)cos(ang);
    }
}

// ---------------------------------------------------------------------------
// LayerNorm: one block per token, 256 threads, float4/thread. bf16 output.
// ---------------------------------------------------------------------------
__global__ __launch_bounds__(256) void ln_kernel(const float* __restrict__ x,
                                                 const float* __restrict__ g,
                                                 const float* __restrict__ b,
                                                 ushort* __restrict__ xn) {
    const size_t t = blockIdx.x;
    const int tid = threadIdx.x;
    const float4 v = ((const float4*)(x + t * HIDDEN))[tid];
    float s = v.x + v.y + v.z + v.w;
#pragma unroll
    for (int off = 32; off > 0; off >>= 1) s += __shfl_down(s, off);
    __shared__ float red[4];
    const int wid = tid >> 6, lane = tid & 63;
    if (lane == 0) red[wid] = s;
    __syncthreads();
    const float mean = (red[0] + red[1] + red[2] + red[3]) * (1.0f / HIDDEN);
    __syncthreads();
    const float dx = v.x - mean, dy = v.y - mean, dz = v.z - mean, dw = v.w - mean;
    float s2 = dx * dx + dy * dy + dz * dz + dw * dw;
#pragma unroll
    for (int off = 32; off > 0; off >>= 1) s2 += __shfl_down(s2, off);
    if (lane == 0) red[wid] = s2;
    __syncthreads();
    const float var = (red[0] + red[1] + red[2] + red[3]) * (1.0f / HIDDEN);
    const float rs = rsqrtf(var + 1e-5f);
    const float4 gv = ((const float4*)g)[tid];
    const float4 bv = ((const float4*)b)[tid];
    ushort4 o;
    o.x = f2bf(dx * rs * gv.x + bv.x);
    o.y = f2bf(dy * rs * gv.y + bv.y);
    o.z = f2bf(dz * rs * gv.z + bv.z);
    o.w = f2bf(dw * rs * gv.w + bv.w);
    ((ushort4*)(xn + t * HIDDEN))[tid] = o;
}

// ---------------------------------------------------------------------------
// 128-tile MFMA core (m97 structure) — for the small BASE slice.
// ---------------------------------------------------------------------------
__device__ __forceinline__ void mfma_core_128(const ushort* __restrict__ A,
                                              const ushort* __restrict__ Bt,
                                              const int lda, const int ldb, const int K,
                                              const int m0, const int n0,
                                              ushort* As, ushort* Bs,
                                              float4x (&acc)[4][4]) {
    const int tid = threadIdx.x;
    const int l = tid & 63, w = tid >> 6;
    const int wm = (w & 1) << 6, wn = (w >> 1) << 6;

    const int c0 = w * 128 + l;
    const int r0 = c0 >> 2, kc0 = (c0 & 3) * 8;
    const int c1 = c0 + 64;
    const int r1 = c1 >> 2, kc1 = (c1 & 3) * 8;
    char* ldsA0 = (char*)As + (size_t)(w * 128) * 16;
    char* ldsA1 = ldsA0 + 1024;
    char* ldsB0 = (char*)Bs + (size_t)(w * 128) * 16;
    char* ldsB1 = ldsB0 + 1024;
    const ushort* gA0 = A + (size_t)(m0 + r0) * lda + kc0;
    const ushort* gA1 = A + (size_t)(m0 + r1) * lda + kc1;
    const ushort* gB0 = Bt + (size_t)(n0 + r0) * ldb + kc0;
    const ushort* gB1 = Bt + (size_t)(n0 + r1) * ldb + kc1;

    const int lr = l & 15, lk = (l >> 4) * 8;
    int aoff[4], boff[4];
#pragma unroll
    for (int i = 0; i < 4; ++i) {
        aoff[i] = (wm + i * 16 + lr) * 32 + lk;
        boff[i] = (wn + i * 16 + lr) * 32 + lk;
    }

    for (int k0 = 0; k0 < K; k0 += 32) {
        __syncthreads();
        ASYNC16(gA0 + k0, ldsA0);
        ASYNC16(gA1 + k0, ldsA1);
        ASYNC16(gB0 + k0, ldsB0);
        ASYNC16(gB1 + k0, ldsB1);
        __syncthreads();
        short8 af[4], bfr[4];
#pragma unroll
        for (int i = 0; i < 4; ++i) af[i] = *(const short8*)(As + aoff[i]);
#pragma unroll
        for (int i = 0; i < 4; ++i) bfr[i] = *(const short8*)(Bs + boff[i]);
#pragma unroll
        for (int mi = 0; mi < 4; ++mi)
#pragma unroll
            for (int ni = 0; ni < 4; ++ni)
                acc[mi][ni] = __builtin_amdgcn_mfma_f32_16x16x32_bf16(
                    af[mi], bfr[ni], acc[mi][ni], 0, 0, 0);
    }
}

template <typename F>
__device__ __forceinline__ void epilogue_loop(const float4x (&acc)[4][4],
                                              int m0, int n0, F body) {
    const int l = threadIdx.x & 63, w = threadIdx.x >> 6;
    const int wm = (w & 1) << 6, wn = (w >> 1) << 6;
    const int lrow = (l >> 4) << 2, lcol = l & 15;
#pragma unroll
    for (int mi = 0; mi < 4; ++mi)
#pragma unroll
        for (int ni = 0; ni < 4; ++ni)
#pragma unroll
            for (int r = 0; r < 4; ++r) {
                const int m = m0 + wm + mi * 16 + lrow + r;
                const int n = n0 + wn + ni * 16 + lcol;
                body(m, n, acc[mi][ni][r]);
            }
}

// ---------------------------------------------------------------------------
// 256x256 deep-pipelined 8-wave MFMA core (best for pv, K=512).
// ---------------------------------------------------------------------------
__device__ __forceinline__ void mfma_core_256(const ushort* __restrict__ A,
                                              const ushort* __restrict__ Bt,
                                              const int lda, const int ldb, const int K,
                                              const int m0, const int n0,
                                              char* smem,
                                              float4x (&acc)[8][4]) {
    const int tid = threadIdx.x;
    const int l = tid & 63, w = tid >> 6;
    const int wm = w >> 2, wn = w & 3;

    const int srow = l >> 2;
    const int kcol = (w & 1) * 32 + (((tid & 3) ^ ((l >> 3) & 3)) << 3);
    const int rb0  = w >> 1;
    const ushort* gA[4];
    const ushort* gB[4];
#pragma unroll
    for (int j = 0; j < 4; ++j) {
        const int row = (j * 4 + rb0) * 16 + srow;
        gA[j] = A  + (size_t)(m0 + row) * lda + kcol;
        gB[j] = Bt + (size_t)(n0 + row) * ldb + kcol;
    }
    char* const ldsA = smem;
    char* const ldsB = smem + 65536;
    const int wdst = w * 1024;

#define STG_A(buf, j, t)  ASYNC16(gA[j] + (size_t)(t) * 64, ldsA + (buf) * 32768 + (j) * 8192 + wdst)
#define STG_B(buf, j, t)  ASYNC16(gB[j] + (size_t)(t) * 64, ldsB + (buf) * 32768 + (j) * 8192 + wdst)
#define RAWBAR() do { __builtin_amdgcn_sched_barrier(0); __builtin_amdgcn_s_barrier(); \
                      __builtin_amdgcn_sched_barrier(0); } while (0)
#define WAITV(N) asm volatile("s_waitcnt vmcnt(" #N ")" ::: "memory")

    const int LB = (l & 15) * 64 + (((l >> 4) ^ ((l >> 1) & 3)) << 4);
    const int rbbA0 = wm * 4;
    const int rbbA1 = 8 + wm * 4;
    const int cbbB0 = wn * 2;
    const int cbbB1 = 8 + wn * 2;

    const int KT = K >> 6;

    STG_A(0, 0, 0); STG_A(0, 1, 0);
    STG_B(0, 0, 0); STG_B(0, 1, 0);
    STG_B(0, 2, 0); STG_B(0, 3, 0);
    STG_A(0, 2, 0); STG_A(0, 3, 0);
    STG_A(1, 0, 1); STG_A(1, 1, 1);
    STG_B(1, 0, 1); STG_B(1, 1, 1);
    STG_B(1, 2, 1); STG_B(1, 3, 1);
    WAITV(10);
    RAWBAR();

    for (int t = 0; t < KT; ++t) {
        const int buf = t & 1;
        const char* Ab = ldsA + buf * 32768;
        const char* Bb = ldsB + buf * 32768;
        short8 a[4][2], b0[2][2], b1[2][2];

#pragma unroll
        for (int mi = 0; mi < 4; ++mi) {
            a[mi][0] = *(const short8*)(Ab + (rbbA0 + mi) * 2048 + LB);
            a[mi][1] = *(const short8*)(Ab + (rbbA0 + mi) * 2048 + 1024 + LB);
        }
#pragma unroll
        for (int ni = 0; ni < 2; ++ni) {
            b0[ni][0] = *(const short8*)(Bb + (cbbB0 + ni) * 2048 + LB);
            b0[ni][1] = *(const short8*)(Bb + (cbbB0 + ni) * 2048 + 1024 + LB);
        }
        if (t + 1 < KT) { STG_A(buf ^ 1, 2, t + 1); STG_A(buf ^ 1, 3, t + 1); }
        RAWBAR();
        __builtin_amdgcn_s_setprio(1);
#pragma unroll
        for (int mi = 0; mi < 4; ++mi)
#pragma unroll
            for (int ni = 0; ni < 2; ++ni) {
                acc[mi][ni] = __builtin_amdgcn_mfma_f32_16x16x32_bf16(a[mi][0], b0[ni][0], acc[mi][ni], 0, 0, 0);
                acc[mi][ni] = __builtin_amdgcn_mfma_f32_16x16x32_bf16(a[mi][1], b0[ni][1], acc[mi][ni], 0, 0, 0);
            }
        __builtin_amdgcn_s_setprio(0);
        if (t < KT - 1) { WAITV(10); } else { WAITV(2); }
        RAWBAR();

#pragma unroll
        for (int ni = 0; ni < 2; ++ni) {
            b1[ni][0] = *(const short8*)(Bb + (cbbB1 + ni) * 2048 + LB);
            b1[ni][1] = *(const short8*)(Bb + (cbbB1 + ni) * 2048 + 1024 + LB);
        }
        if (t + 2 < KT) { STG_A(buf, 0, t + 2); STG_A(buf, 1, t + 2); }
        RAWBAR();
        __builtin_amdgcn_s_setprio(1);
#pragma unroll
        for (int mi = 0; mi < 4; ++mi)
#pragma unroll
            for (int ni = 0; ni < 2; ++ni) {
                acc[mi][2 + ni] = __builtin_amdgcn_mfma_f32_16x16x32_bf16(a[mi][0], b1[ni][0], acc[mi][2 + ni], 0, 0, 0);
                acc[mi][2 + ni] = __builtin_amdgcn_mfma_f32_16x16x32_bf16(a[mi][1], b1[ni][1], acc[mi][2 + ni], 0, 0, 0);
            }
        __builtin_amdgcn_s_setprio(0);
        if (t < KT - 2) { WAITV(10); } else if (t == KT - 2) { WAITV(8); } else { WAITV(0); }
        RAWBAR();

#pragma unroll
        for (int mi = 0; mi < 4; ++mi) {
            a[mi][0] = *(const short8*)(Ab + (rbbA1 + mi) * 2048 + LB);
            a[mi][1] = *(const short8*)(Ab + (rbbA1 + mi) * 2048 + 1024 + LB);
        }
        if (t + 2 < KT) {
            STG_B(buf, 0, t + 2); STG_B(buf, 1, t + 2);
            STG_B(buf, 2, t + 2); STG_B(buf, 3, t + 2);
        }
        RAWBAR();
        __builtin_amdgcn_s_setprio(1);
#pragma unroll
        for (int mi = 0; mi < 4; ++mi)
#pragma unroll
            for (int ni = 0; ni < 2; ++ni) {
                acc[4 + mi][2 + ni] = __builtin_amdgcn_mfma_f32_16x16x32_bf16(a[mi][0], b1[ni][0], acc[4 + mi][2 + ni], 0, 0, 0);
                acc[4 + mi][2 + ni] = __builtin_amdgcn_mfma_f32_16x16x32_bf16(a[mi][1], b1[ni][1], acc[4 + mi][2 + ni], 0, 0, 0);
            }
#pragma unroll
        for (int mi = 0; mi < 4; ++mi)
#pragma unroll
            for (int ni = 0; ni < 2; ++ni) {
                acc[4 + mi][ni] = __builtin_amdgcn_mfma_f32_16x16x32_bf16(a[mi][0], b0[ni][0], acc[4 + mi][ni], 0, 0, 0);
                acc[4 + mi][ni] = __builtin_amdgcn_mfma_f32_16x16x32_bf16(a[mi][1], b0[ni][1], acc[4 + mi][ni], 0, 0, 0);
            }
        __builtin_amdgcn_s_setprio(0);
        if (t < KT - 2) { WAITV(10); } else if (t == KT - 2) { WAITV(4); }
        RAWBAR();
    }
#undef STG_A
#undef STG_B
#undef RAWBAR
#undef WAITV
}

template <typename F>
__device__ __forceinline__ void epilogue_256(const float4x (&acc)[8][4],
                                             int m0, int n0, F body) {
    const int tid = threadIdx.x;
    const int l = tid & 63, w = tid >> 6;
    const int wm = w >> 2, wn = w & 3;
    const int lrow = (l >> 4) << 2, lcol = l & 15;
#pragma unroll
    for (int i = 0; i < 8; ++i)
#pragma unroll
        for (int j = 0; j < 4; ++j)
#pragma unroll
            for (int r = 0; r < 4; ++r) {
                const int m = m0 + (i >> 2) * 128 + wm * 64 + (i & 3) * 16 + lrow + r;
                const int n = n0 + (j >> 1) * 128 + wn * 32 + (j & 1) * 16 + lcol;
                body(m, n, acc[i][j][r]);
            }
}

// ---------------------------------------------------------------------------
// 256x256 16-wave v3 core (measured 859 TF @ K=1024).
// ---------------------------------------------------------------------------
__device__ __forceinline__ void mfma_core_v3(const ushort* __restrict__ A,
                                             const ushort* __restrict__ Bt,
                                             const int lda, const int ldb, const int K,
                                             const int m0, const int n0,
                                             char* smem,
                                             float4x (&acc)[4][4]) {
    const int tid = threadIdx.x;
    const int l = tid & 63, w = tid >> 6;        // 16 waves
    const int wm = w >> 2, wn = w & 3;

    const int srow = l >> 2;
    const int kswz = ((l & 3) ^ ((l >> 3) & 3)) << 3;
    const ushort* gA = A + (size_t)(m0 + w * 16 + srow) * lda + kswz;
    const ushort* gB = Bt + (size_t)(n0 + w * 16 + srow) * ldb + kswz;
    char* const ldsA = smem;
    char* const ldsB = smem + 65536;
    const int woff = w * 2048;

    const int LB = (l & 15) * 64 + (((l >> 4) ^ ((l >> 1) & 3)) << 4);
    const int rbb = wm * 4, cbb = wn * 4;
    const int KT = K >> 6;

    ASYNC16(gA, ldsA + woff);
    ASYNC16(gA + 32, ldsA + woff + 1024);
    ASYNC16(gB, ldsB + woff);
    ASYNC16(gB + 32, ldsB + woff + 1024);
    __syncthreads();

    for (int t = 0; t < KT; ++t) {
        const int buf = t & 1;
        const char* Ab = ldsA + buf * 32768;
        const char* Bb = ldsB + buf * 32768;
        if (t + 1 < KT) {
            const size_t g = (size_t)(t + 1) * 64;
            char* dA = ldsA + (buf ^ 1) * 32768 + woff;
            char* dB = ldsB + (buf ^ 1) * 32768 + woff;
            ASYNC16(gA + g, dA);
            ASYNC16(gA + g + 32, dA + 1024);
            ASYNC16(gB + g, dB);
            ASYNC16(gB + g + 32, dB + 1024);
        }
        __builtin_amdgcn_sched_barrier(0);
#pragma unroll
        for (int kh = 0; kh < 2; ++kh) {
            short8 a[4], b[4];
#pragma unroll
            for (int i = 0; i < 4; ++i) {
                a[i] = *(const short8*)(Ab + (rbb + i) * 2048 + kh * 1024 + LB);
                b[i] = *(const short8*)(Bb + (cbb + i) * 2048 + kh * 1024 + LB);
            }
            __builtin_amdgcn_s_setprio(1);
#pragma unroll
            for (int i = 0; i < 4; ++i)
#pragma unroll
                for (int j = 0; j < 4; ++j)
                    acc[i][j] = __builtin_amdgcn_mfma_f32_16x16x32_bf16(
                        a[i], b[j], acc[i][j], 0, 0, 0);
            __builtin_amdgcn_s_setprio(0);
        }
        __syncthreads();
    }
}

template <typename F>
__device__ __forceinline__ void epilogue_v3(const float4x (&acc)[4][4],
                                            int m0, int n0, F body) {
    const int tid = threadIdx.x;
    const int l = tid & 63, w = tid >> 6;
    const int wm = w >> 2, wn = w & 3;
    const int lrow = (l >> 4) << 2, lcol = l & 15;
#pragma unroll
    for (int i = 0; i < 4; ++i)
#pragma unroll
        for (int j = 0; j < 4; ++j)
#pragma unroll
            for (int r = 0; r < 4; ++r) {
                const int m = m0 + wm * 64 + i * 16 + lrow + r;
                const int n = n0 + wn * 64 + j * 16 + lcol;
                body(m, n, acc[i][j][r]);
            }
}

// ---------------------------------------------------------------------------
// GEMM1 (U/V part): v3 core, 16-col grid (measured: FETCH 147MB, 165 us).
// ---------------------------------------------------------------------------
__global__ __launch_bounds__(1024, 4) void gemm_uv3(const ushort* __restrict__ A,
                                                    const ushort* __restrict__ Bt,
                                                    const float* __restrict__ bias,
                                                    ushort* __restrict__ U,
                                                    ushort* __restrict__ VT) {
    __shared__ __align__(16) char smem[131072];
    float4x acc[4][4] = {};
    const int n0 = blockIdx.x * 256, m0 = blockIdx.y * 256;
    mfma_core_v3(A, Bt, HIDDEN, HIDDEN, HIDDEN, m0, n0, smem, acc);
    if (blockIdx.x < 8) {
        epilogue_v3(acc, m0, n0, [&](int m, int n, float aval) {
            float val = aval + bias[n];
            val = val / (1.0f + expf(-val));
            U[(size_t)m * EDIM + n] = f2bf(val);
        });
    } else {
        epilogue_v3(acc, m0, n0, [&](int m, int n, float aval) {
            float val = aval + bias[n];
            val = val / (1.0f + expf(-val));
            const int e = n - EDIM;
            const int b = m >> 9;
            const int s = m & (NSEQ - 1);
            VT[((size_t)b * EDIM + e) * NSEQ + s] = f2bf(val);
        });
    }
}

// ---------------------------------------------------------------------------
// GEMM1 (BASE slice, 128 cols): 128-tile core, separate kernel.
// ---------------------------------------------------------------------------
__global__ __launch_bounds__(256) void gemm_base_mfma(const ushort* __restrict__ A,
                                                      const ushort* __restrict__ Bt,
                                                      const float* __restrict__ bias,
                                                      float* __restrict__ BASE) {
    __shared__ ushort As[128 * 32], Bs[128 * 32];
    float4x acc[4][4] = {};
    const int n0 = 2 * EDIM;                 // 4096
    const int m0 = blockIdx.y * 128;
    mfma_core_128(A, Bt, HIDDEN, HIDDEN, HIDDEN, m0, n0, As, Bs, acc);
    epilogue_loop(acc, m0, n0, [&](int m, int n, float aval) {
        float val = aval + bias[n];
        val = val / (1.0f + expf(-val));
        BASE[(size_t)m * SDIM + (n - 2 * EDIM)] = val;
    });
}

// ---------------------------------------------------------------------------
// Rope: base(r,128) -> q,k split into bf16 head + bf16 residual.
// ---------------------------------------------------------------------------
__global__ __launch_bounds__(128) void rope_kernel(const float* __restrict__ base,
                                                   const float* __restrict__ gamma,
                                                   const float* __restrict__ beta,
                                                   const float* __restrict__ sin_t,
                                                   const float* __restrict__ cos_t,
                                                   ushort* __restrict__ qh,
                                                   ushort* __restrict__ ql,
                                                   ushort* __restrict__ kh,
                                                   ushort* __restrict__ kl) {
    const size_t t = blockIdx.x;
    const int d = threadIdx.x;
    const int pos = (int)(t & (NSEQ - 1));
    __shared__ float vq[128], vk[128];
    const float bval = base[t * SDIM + d];
    vq[d] = bval * gamma[d] + beta[d];
    vk[d] = bval * gamma[SDIM + d] + beta[SDIM + d];
    __syncthreads();
    const int h = d & 63;
    const float sn = sin_t[pos * 64 + h];
    const float cs = cos_t[pos * 64 + h];
    float oq, ok;
    if (d < 64) {
        oq = vq[d] * cs - vq[d + 64] * sn;
        ok = vk[d] * cs - vk[d + 64] * sn;
    } else {
        oq = vq[d] * cs + vq[d - 64] * sn;
        ok = vk[d] * cs + vk[d - 64] * sn;
    }
    const ushort qhv = f2bf(oq);
    const ushort khv = f2bf(ok);
    qh[t * SDIM + d] = qhv;
    ql[t * SDIM + d] = f2bf(oq - bf2f(qhv));
    kh[t * SDIM + d] = khv;
    kl[t * SDIM + d] = f2bf(ok - bf2f(khv));
}

// ---------------------------------------------------------------------------
// QK^T per batch via bf16x3 MFMA: qk = qh*kh + qh*kl + ql*kh.
// ---------------------------------------------------------------------------
__global__ __launch_bounds__(256, 4) void gemm_qk3(const ushort* __restrict__ qh,
                                                   const ushort* __restrict__ ql,
                                                   const ushort* __restrict__ kh,
                                                   const ushort* __restrict__ kl,
                                                   const float* __restrict__ mask,
                                                   const float* __restrict__ w,
                                                   ushort* __restrict__ km) {
    __shared__ __align__(16) char smem[32768];
    float4x acc[4][4] = {};
    const int b = blockIdx.z;
    const int tid = threadIdx.x;
    const int l = tid & 63, wv = tid >> 6;
    const int wm = wv & 1, wn = wv >> 1;
    const int m0 = blockIdx.y * 128, n0 = blockIdx.x * 128;
    const size_t boff = (size_t)b * NSEQ * SDIM;

    const int srow = l >> 2;
    const int kswz = ((l & 3) ^ ((l >> 3) & 3)) << 3;
    const size_t r0 = (size_t)(m0 + wv * 16 + srow) * SDIM + kswz;
    const size_t r1 = r0 + (size_t)64 * SDIM;
    const size_t c0 = (size_t)(n0 + wv * 16 + srow) * SDIM + kswz;
    const size_t c1 = c0 + (size_t)64 * SDIM;
    const ushort* gqh = qh + boff;
    const ushort* gql = ql + boff;
    const ushort* gkh = kh + boff;
    const ushort* gkl = kl + boff;

    const int LB = (l & 15) * 64 + (((l >> 4) ^ ((l >> 1) & 3)) << 4);

    for (int t = 0; t < 4; ++t) {
        const int g = t * 32;
        ASYNC16(gqh + r0 + g, smem + wv * 1024);
        ASYNC16(gqh + r1 + g, smem + (4 + wv) * 1024);
        ASYNC16(gql + r0 + g, smem + 8192 + wv * 1024);
        ASYNC16(gql + r1 + g, smem + 8192 + (4 + wv) * 1024);
        ASYNC16(gkh + c0 + g, smem + 16384 + wv * 1024);
        ASYNC16(gkh + c1 + g, smem + 16384 + (4 + wv) * 1024);
        ASYNC16(gkl + c0 + g, smem + 24576 + wv * 1024);
        ASYNC16(gkl + c1 + g, smem + 24576 + (4 + wv) * 1024);
        __syncthreads();
        short8 ah[4], bh[4], bl[4];
#pragma unroll
        for (int i = 0; i < 4; ++i) {
            ah[i] = *(const short8*)(smem + (wm * 4 + i) * 1024 + LB);
            bh[i] = *(const short8*)(smem + 16384 + (wn * 4 + i) * 1024 + LB);
            bl[i] = *(const short8*)(smem + 24576 + (wn * 4 + i) * 1024 + LB);
        }
        __builtin_amdgcn_s_setprio(1);
#pragma unroll
        for (int i = 0; i < 4; ++i)
#pragma unroll
            for (int j = 0; j < 4; ++j) {
                acc[i][j] = __builtin_amdgcn_mfma_f32_16x16x32_bf16(ah[i], bh[j], acc[i][j], 0, 0, 0);
                acc[i][j] = __builtin_amdgcn_mfma_f32_16x16x32_bf16(ah[i], bl[j], acc[i][j], 0, 0, 0);
            }
        __builtin_amdgcn_s_setprio(0);
        short8 al[4];
#pragma unroll
        for (int i = 0; i < 4; ++i)
            al[i] = *(const short8*)(smem + 8192 + (wm * 4 + i) * 1024 + LB);
        __builtin_amdgcn_s_setprio(1);
#pragma unroll
        for (int i = 0; i < 4; ++i)
#pragma unroll
            for (int j = 0; j < 4; ++j)
                acc[i][j] = __builtin_amdgcn_mfma_f32_16x16x32_bf16(al[i], bh[j], acc[i][j], 0, 0, 0);
        __builtin_amdgcn_s_setprio(0);
        if (t < 3) __syncthreads();
    }

    const int lrow = (l >> 4) << 2, lcol = l & 15;
    const float inv512 = 1.0f / 512.0f;
#pragma unroll
    for (int i = 0; i < 4; ++i)
#pragma unroll
        for (int j = 0; j < 4; ++j)
#pragma unroll
            for (int r = 0; r < 4; ++r) {
                const int m = m0 + wm * 64 + i * 16 + lrow + r;
                const int n = n0 + wn * 64 + j * 16 + lcol;
                const float mterm = (1.0f - mask[b * NSEQ + n]) * -1e12f;
                float val = (acc[i][j][r] + mterm) * inv512 + w[511 + n - m];
                val = fmaxf(val, 0.0f);
                km[(size_t)b * NSEQ * NSEQ + (size_t)m * NSEQ + n] = f2bf(val * val);
            }
}

// ---------------------------------------------------------------------------
// kernel @ V per batch (8-wave 256 core, K=512), gated by u in-place.
// ---------------------------------------------------------------------------
__global__ __launch_bounds__(512) void gemm_pv2(const ushort* __restrict__ km,
                                                const ushort* __restrict__ vT,
                                                ushort* __restrict__ ug) {
    __shared__ __align__(16) char smem[131072];
    float4x acc[8][4] = {};
    const int b = blockIdx.z;
    const int n0 = blockIdx.x * 256, m0 = blockIdx.y * 256;
    mfma_core_256(km + (size_t)b * NSEQ * NSEQ, vT + (size_t)b * EDIM * NSEQ,
                  NSEQ, NSEQ, NSEQ, m0, n0, smem, acc);
    const size_t tokbase = (size_t)b * NSEQ;
    epilogue_256(acc, m0, n0, [&](int m, int n, float aval) {
        const size_t idx = (tokbase + m) * EDIM + n;
        ug[idx] = f2bf(bf2f(ug[idx]) * aval);
    });
}

// ---------------------------------------------------------------------------
// GEMM2: out = gated @ o_w + o_b + x (v3 16-wave core, K=2048, fp32 out).
// ---------------------------------------------------------------------------
__global__ __launch_bounds__(1024, 4) void gemm_out5(const ushort* __restrict__ A,
                                                     const ushort* __restrict__ Bt,
                                                     const float* __restrict__ ob,
                                                     const float* __restrict__ x,
                                                     float* __restrict__ out) {
    __shared__ __align__(16) char smem[131072];
    float4x acc[4][4] = {};
    const int n0 = blockIdx.x * 256, m0 = blockIdx.y * 256;
    mfma_core_v3(A, Bt, EDIM, EDIM, EDIM, m0, n0, smem, acc);
    epilogue_v3(acc, m0, n0, [&](int m, int n, float aval) {
        out[(size_t)m * HIDDEN + n] = aval + ob[n] + x[(size_t)m * HIDDEN + n];
    });
}

// ---------------------------------------------------------------------------
// Workspace: need = C*5505024 + 13107200 bytes (unchanged).
// xn overlay after gemm_uv: qh/ql/kh/kl bf16 (C*131072 each) + km bf16.
// ---------------------------------------------------------------------------
extern "C" void kernel_launch(void* const* d_in, const int* in_sizes, int n_in,
                              void* d_out, int out_size, void* d_ws, size_t ws_size,
                              hipStream_t stream) {
    const float* x     = (const float*)d_in[0];
    const float* mask  = (const float*)d_in[1];
    const float* gamma = (const float*)d_in[2];
    const float* beta  = (const float*)d_in[3];
    const float* w     = (const float*)d_in[4];
    const float* uv_w  = (const float*)d_in[7];
    const float* uv_b  = (const float*)d_in[8];
    const float* o_w   = (const float*)d_in[9];
    const float* o_b   = (const float*)d_in[10];
    const float* ln_g  = (const float*)d_in[11];
    const float* ln_b  = (const float*)d_in[12];
    float* out = (float*)d_out;

    int C = 32;
    while (C > 1) {
        unsigned long long need = (unsigned long long)C * 5505024ull + 13107200ull;
        if (need <= (unsigned long long)ws_size) break;
        C >>= 1;
    }
    const int R = C * NSEQ;

    char* p = (char*)d_ws;
    ushort* xn  = (ushort*)p;  p += (size_t)C * 1048576;
    ushort* u   = (ushort*)p;  p += (size_t)C * 2097152;
    ushort* vT  = (ushort*)p;  p += (size_t)C * 2097152;
    float* base = (float*)p;   p += (size_t)C * 262144;
    float* sint = (float*)p;   p += 131072;
    float* cost = (float*)p;   p += 131072;
    ushort* uv_wt = (ushort*)p; p += 8650752;
    ushort* o_wt  = (ushort*)p; p += 4194304;
    ushort* qh = (ushort*)xn;
    ushort* ql = (ushort*)((char*)xn + (size_t)C * 131072);
    ushort* kh = (ushort*)((char*)xn + (size_t)C * 262144);
    ushort* kl = (ushort*)((char*)xn + (size_t)C * 393216);
    ushort* km = (ushort*)((char*)xn + (size_t)C * 524288);

    hipLaunchKernelGGL(prep_kernel, dim3(6400), dim3(256), 0, stream,
                       uv_w, uv_wt, o_w, o_wt, sint, cost);

    for (int b0 = 0; b0 < BATCH; b0 += C) {
        const float* xc = x + (size_t)b0 * NSEQ * HIDDEN;
        float*       oc = out + (size_t)b0 * NSEQ * HIDDEN;
        const float* mc = mask + (size_t)b0 * NSEQ;
        hipLaunchKernelGGL(ln_kernel, dim3(R), dim3(256), 0, stream, xc, ln_g, ln_b, xn);
        hipLaunchKernelGGL(gemm_uv3, dim3(16, R / 256), dim3(1024), 0, stream,
                           xn, uv_wt, uv_b, u, vT);
        hipLaunchKernelGGL(gemm_base_mfma, dim3(1, R / 128), dim3(256), 0, stream,
                           xn, uv_wt, uv_b, base);
        hipLaunchKernelGGL(rope_kernel, dim3(R), dim3(128), 0, stream,
                           base, gamma, beta, sint, cost, qh, ql, kh, kl);
        hipLaunchKernelGGL(gemm_qk3, dim3(4, 4, C), dim3(256), 0, stream,
                           qh, ql, kh, kl, mc, w, km);
        hipLaunchKernelGGL(gemm_pv2, dim3(8, 2, C), dim3(512), 0, stream, km, vT, u);
        hipLaunchKernelGGL(gemm_out5, dim3(4, R / 256), dim3(1024), 0, stream,
                           u, o_wt, o_b, xc, oc);
    }
}